// Round 1
// baseline (3329.020 us; speedup 1.0000x reference)
//
#include <hip/hip_runtime.h>

// Problem constants (from reference): T=2048, B=256, F=64, H=256, O=1
#define T_STEPS 2048
#define BATCH   256
#define FEAT    64
#define HID     256
#define KAUG    320   // FEAT + HID

// fast tanh: tanh(z) = 1 - 2/(exp(2z)+1). v_exp_f32 + v_rcp_f32, ~1e-6 abs err.
// Saturates correctly: z->+inf => e=inf => rcp=0 => 1; z->-inf => e=0 => -1.
__device__ __forceinline__ float fast_tanh(float z) {
    float e = __expf(2.0f * z);
    return 1.0f - 2.0f * __builtin_amdgcn_rcpf(e + 1.0f);
}

// One block per batch element. 256 threads = 4 waves (1 wave/SIMD, 1 block/CU).
// Wave w owns k-range [80w, 80w+80) of augmented input a=[x_t; h].
// Lane l owns neurons j = 4l..4l+3. Weights register-resident: 320 VGPR/lane.
__global__ void __launch_bounds__(256, 1)
rnn_kernel(const float* __restrict__ x,    // (T, B, F)
           const float* __restrict__ W0,   // (H, F+H) row-major
           const float* __restrict__ b0,   // (H)
           const float* __restrict__ Wfc,  // (1, H)
           const float* __restrict__ bfc,  // (1)
           float* __restrict__ out)        // (B, T), pre-zeroed
{
    const int b    = blockIdx.x;
    const int tid  = threadIdx.x;
    const int w    = tid >> 6;
    const int lane = tid & 63;
    const int kbase = 80 * w;

    __shared__ float a_buf[2][KAUG];   // double-buffered augmented input
    __shared__ float part[4][HID];     // per-wave partial sums

    // ---- load register-resident weights: wreg[kk][n] = W0[4*lane+n][kbase+kk]
    float wreg[80][4];
#pragma unroll
    for (int kk = 0; kk < 80; ++kk) {
#pragma unroll
        for (int n = 0; n < 4; ++n) {
            wreg[kk][n] = W0[(4 * lane + n) * KAUG + kbase + kk];
        }
    }

    const float b0_r  = b0[tid];    // neuron tid's bias (used in reduce phase)
    const float wfc_r = Wfc[tid];   // fc weight for neuron tid
    const float bfc_r = bfc[0];

    // ---- prologue: a_buf[0] = [x_0 ; h0=0]
    if (tid < FEAT) a_buf[0][tid] = x[b * FEAT + tid];
    a_buf[0][FEAT + tid] = 0.0f;
    __syncthreads();

    for (int t = 0; t < T_STEPS; ++t) {
        const int cur = t & 1;
        const int nxt = cur ^ 1;

        // prefetch x for step t+1 (latency hidden under FMA phase)
        float xnext = 0.0f;
        if (tid < FEAT) {
            int tn = (t + 1 < T_STEPS) ? (t + 1) : t;
            xnext = x[tn * (BATCH * FEAT) + b * FEAT + tid];
        }

        // ---- FMA phase: 320 fp32 FMAs/lane, 4 independent acc chains
        float acc[4] = {0.f, 0.f, 0.f, 0.f};
        const float4* a4 = reinterpret_cast<const float4*>(&a_buf[cur][kbase]);
#pragma unroll
        for (int c = 0; c < 20; ++c) {
            float4 av = a4[c];   // uniform address -> LDS broadcast, conflict-free
            float avf[4] = {av.x, av.y, av.z, av.w};
#pragma unroll
            for (int i = 0; i < 4; ++i) {
#pragma unroll
                for (int n = 0; n < 4; ++n) {
                    acc[n] = fmaf(wreg[4 * c + i][n], avf[i], acc[n]);
                }
            }
        }

        // partials: part[w][4l..4l+3], contiguous b128 write
        *reinterpret_cast<float4*>(&part[w][4 * lane]) =
            make_float4(acc[0], acc[1], acc[2], acc[3]);
        __syncthreads();

        // ---- reduce phase: thread tid owns neuron j = tid
        float s = part[0][tid] + part[1][tid] + part[2][tid] + part[3][tid] + b0_r;
        float h = fast_tanh(s);
        a_buf[nxt][FEAT + tid] = h;
        if (tid < FEAT) a_buf[nxt][tid] = xnext;

        // output: out[b][t] = sum_j Wfc[j]*h[j] + bfc
        float p = wfc_r * h;
#pragma unroll
        for (int m = 32; m >= 1; m >>= 1) p += __shfl_xor(p, m, 64);
        if (lane == 0) {
            float add = p + (w == 0 ? bfc_r : 0.0f);
            atomicAdd(&out[b * T_STEPS + t], add);
        }
        __syncthreads();   // a_buf[nxt] complete before next step reads it
    }
}

extern "C" void kernel_launch(void* const* d_in, const int* in_sizes, int n_in,
                              void* d_out, int out_size, void* d_ws, size_t ws_size,
                              hipStream_t stream) {
    const float* x   = (const float*)d_in[0];
    const float* W0  = (const float*)d_in[1];
    const float* b0  = (const float*)d_in[2];
    const float* Wfc = (const float*)d_in[3];
    const float* bfc = (const float*)d_in[4];
    // d_in[5] = feature_n == 0 -> no autoregressive tail
    float* out = (float*)d_out;

    hipMemsetAsync(out, 0, (size_t)out_size * sizeof(float), stream);
    rnn_kernel<<<dim3(BATCH), dim3(256), 0, stream>>>(x, W0, b0, Wfc, bfc, out);
}

// Round 2
// 2400.068 us; speedup vs baseline: 1.3871x; 1.3871x over previous
//
#include <hip/hip_runtime.h>

// Problem constants: T=2048, B=256, F=64, H=256, O=1
#define T_STEPS 2048
#define BATCH   256
#define FEAT    64
#define HID     256
#define KAUG    320   // FEAT + HID
#define NW      8     // waves per block
#define KCH     40    // KAUG / NW  (k-chunk per wave)

// fast tanh: tanh(z) = 1 - 2/(exp(2z)+1). Saturates correctly at +/-inf.
__device__ __forceinline__ float fast_tanh(float z) {
    float e = __expf(2.0f * z);
    return 1.0f - 2.0f * __builtin_amdgcn_rcpf(e + 1.0f);
}

// One block per batch element, 512 threads = 8 waves = 2 waves/SIMD, 1 block/CU.
// Wave w owns k-range [40w, 40w+40) of augmented input a=[x_t; h].
// Lane l owns neurons j = 4l..4l+3.
// Weights register-resident: wreg[40][4] = 160 VGPRs/lane (fits 256-VGPR arch cap;
// round 1's 320/lane spilled to scratch -> 64MB WRITE_SIZE, VALUBusy 31%).
__global__ void __launch_bounds__(512, 2)
rnn_kernel(const float* __restrict__ x,    // (T, B, F)
           const float* __restrict__ W0,   // (H, F+H) row-major
           const float* __restrict__ b0,   // (H)
           const float* __restrict__ Wfc,  // (1, H)
           const float* __restrict__ bfc,  // (1)
           float* __restrict__ out)        // (B, T), pre-zeroed
{
    const int b    = blockIdx.x;
    const int tid  = threadIdx.x;
    const int w    = tid >> 6;
    const int lane = tid & 63;
    const int kbase = KCH * w;

    __shared__ float a_buf[2][KAUG];   // double-buffered augmented input
    __shared__ float part[NW][HID];    // per-wave partial sums

    // wreg[kk][n] = W0[4*lane+n][kbase+kk]   (160 VGPRs)
    float wreg[KCH][4];
#pragma unroll
    for (int kk = 0; kk < KCH; ++kk) {
#pragma unroll
        for (int n = 0; n < 4; ++n) {
            wreg[kk][n] = W0[(4 * lane + n) * KAUG + kbase + kk];
        }
    }

    float b0_r = 0.0f, wfc_r = 0.0f;
    if (tid < HID) { b0_r = b0[tid]; wfc_r = Wfc[tid]; }
    const float bfc_r = bfc[0];

    // prologue: a_buf[0] = [x_0 ; h0=0]
    if (tid < FEAT) a_buf[0][tid] = x[b * FEAT + tid];
    if (tid < HID)  a_buf[0][FEAT + tid] = 0.0f;
    __syncthreads();

    for (int t = 0; t < T_STEPS; ++t) {
        const int cur = t & 1;
        const int nxt = cur ^ 1;

        // prefetch x for step t+1 (hidden under FMA phase)
        float xnext = 0.0f;
        if (tid < FEAT) {
            int tn = (t + 1 < T_STEPS) ? (t + 1) : t;
            xnext = x[tn * (BATCH * FEAT) + b * FEAT + tid];
        }

        // ---- FMA phase: 160 fp32 FMAs/lane, 4 independent acc chains,
        // fed by 10 uniform-address ds_read_b128 broadcasts (conflict-free)
        float acc[4] = {0.f, 0.f, 0.f, 0.f};
        const float4* a4 = reinterpret_cast<const float4*>(&a_buf[cur][kbase]);
#pragma unroll
        for (int c = 0; c < KCH / 4; ++c) {
            float4 av = a4[c];
            const float avf[4] = {av.x, av.y, av.z, av.w};
#pragma unroll
            for (int i = 0; i < 4; ++i) {
#pragma unroll
                for (int n = 0; n < 4; ++n) {
                    acc[n] = fmaf(wreg[4 * c + i][n], avf[i], acc[n]);
                }
            }
        }

        // partials: contiguous b128 store, conflict-free
        *reinterpret_cast<float4*>(&part[w][4 * lane]) =
            make_float4(acc[0], acc[1], acc[2], acc[3]);
        __syncthreads();

        // ---- reduce phase: waves 0-3 active, thread tid owns neuron tid
        if (tid < HID) {
            float s = b0_r;
#pragma unroll
            for (int ww = 0; ww < NW; ++ww) s += part[ww][tid];
            float h = fast_tanh(s);
            a_buf[nxt][FEAT + tid] = h;
            if (tid < FEAT) a_buf[nxt][tid] = xnext;

            // out[b][t] = Wfc . h + bfc
            float p = wfc_r * h;
#pragma unroll
            for (int m = 32; m >= 1; m >>= 1) p += __shfl_xor(p, m, 64);
            if (lane == 0) {
                atomicAdd(&out[b * T_STEPS + t], p + (w == 0 ? bfc_r : 0.0f));
            }
        }
        __syncthreads();   // a_buf[nxt] complete before next step's FMA phase
    }
}

extern "C" void kernel_launch(void* const* d_in, const int* in_sizes, int n_in,
                              void* d_out, int out_size, void* d_ws, size_t ws_size,
                              hipStream_t stream) {
    const float* x   = (const float*)d_in[0];
    const float* W0  = (const float*)d_in[1];
    const float* b0  = (const float*)d_in[2];
    const float* Wfc = (const float*)d_in[3];
    const float* bfc = (const float*)d_in[4];
    // d_in[5] = feature_n == 0 -> no autoregressive tail
    float* out = (float*)d_out;

    hipMemsetAsync(out, 0, (size_t)out_size * sizeof(float), stream);
    rnn_kernel<<<dim3(BATCH), dim3(512), 0, stream>>>(x, W0, b0, Wfc, bfc, out);
}